// Round 16
// baseline (395.675 us; speedup 1.0000x reference)
//
#include <hip/hip_runtime.h>
#include <hip/hip_bf16.h>

#define NN 50000
#define NE 800000
#define F 128     // input feature dim (= K)
#define HD 128    // output dim = H*DH (= N)
#define H 4

typedef __attribute__((ext_vector_type(4))) float f32x4;
typedef __attribute__((ext_vector_type(8))) __bf16 bf16x8;
typedef __attribute__((ext_vector_type(2))) __bf16 bf16x2;

// ---------- helpers ----------

// mish(x) = x * tanh(softplus(x)) = x * (u-1)/(u+1), u = (1+e^x)^2
__device__ __forceinline__ float mish_f(float x) {
    if (x > 30.f) return x;
    float t = __expf(x);
    float u = 1.f + t;
    u = u * u;
    return x * (u - 1.f) * __builtin_amdgcn_rcpf(u + 1.f);
}

// packed f32x2 -> bf16x2 (compiler emits v_cvt_pk_bf16_f32, RNE)
__device__ __forceinline__ unsigned pack2_bf16(float a, float b) {
    bf16x2 v;
    v.x = (__bf16)a;
    v.y = (__bf16)b;
    return __builtin_bit_cast(unsigned, v);
}
__device__ __forceinline__ float bf16lo_to_f32(unsigned p) {
    return __uint_as_float((p & 0xFFFFu) << 16);
}
__device__ __forceinline__ float bf16hi_to_f32(unsigned p) {
    return __uint_as_float(p & 0xFFFF0000u);
}

// DPP-based add: v += lane-permuted v within a row of 16 (VALU, no DS)
#define DPP_ADD(v, ctrl)                                                     \
    (v) += __int_as_float(__builtin_amdgcn_update_dpp(                       \
        0, __float_as_int(v), (ctrl), 0xf, 0xf, true))
#define DPP_REDUCE16(v) do {                                                 \
    DPP_ADD(v, 0xB1);  DPP_ADD(v, 0x4E);                                     \
    DPP_ADD(v, 0x141); DPP_ADD(v, 0x140); } while (0)

// ---------- prep: W -> bf16 fragment-ordered; extra blocks zero cnt/cnt2 ----------
__global__ __launch_bounds__(256) void prep_w(
    const float* __restrict__ W0, const float* __restrict__ W1,
    const float* __restrict__ W2, uint4* __restrict__ O,
    uint4* __restrict__ zero_dst)   // 400,000 B = 25,000 uint4
{
    int b = blockIdx.x;
    if (b >= 3) {
        int i = (b - 3) * 256 + threadIdx.x;
        if (i < 25000) zero_dst[i] = make_uint4(0, 0, 0, 0);
        return;
    }
    const float* W = (b == 0) ? W0 : (b == 1) ? W1 : W2;
    uint4* out = O + b * 2048;
    for (int c = threadIdx.x; c < 2048; c += 256) {
        int fn = c >> 8, ks = (c >> 6) & 3, lane = c & 63;
        int lgp = lane >> 4, l15 = lane & 15;
        int col = fn * 16 + l15, k0 = ks * 32 + lgp * 8;
        unsigned u[4];
        #pragma unroll
        for (int i = 0; i < 4; ++i)
            u[i] = pack2_bf16(W[(k0 + 2 * i) * 128 + col],
                              W[(k0 + 2 * i + 1) * 128 + col]);
        out[c] = make_uint4(u[0], u[1], u[2], u[3]);
    }
}

// ---------- CSR build ----------
__global__ __launch_bounds__(256) void hist_kernel(
    const int* __restrict__ receivers, unsigned* __restrict__ cnt)
{
    int i = blockIdx.x * 256 + threadIdx.x;
    if (i < NE) atomicAdd(&cnt[receivers[i]], 1u);
}

// scan phase 1: per-block exclusive scan of 256 counts + block sum
__global__ __launch_bounds__(256) void scan1_kernel(
    const unsigned* __restrict__ cnt, unsigned* __restrict__ rowptr,
    unsigned* __restrict__ bsum)
{
    __shared__ unsigned sh[256];
    const int t = threadIdx.x;
    int i = blockIdx.x * 256 + t;
    unsigned c = (i < NN) ? cnt[i] : 0u;
    sh[t] = c;
    __syncthreads();
    unsigned incl = c;
    for (int off = 1; off < 256; off <<= 1) {
        unsigned v = (t >= off) ? sh[t - off] : 0u;
        __syncthreads();
        incl += v;
        sh[t] = incl;
        __syncthreads();
    }
    if (i < NN) rowptr[i] = incl - c;      // exclusive within block
    if (t == 255) bsum[blockIdx.x] = incl; // block total
}

// scan phase 2+3 fused
__global__ __launch_bounds__(256) void scan3_kernel(
    unsigned* __restrict__ rowptr, const unsigned* __restrict__ bsum, int nb)
{
    __shared__ unsigned sh[256];
    __shared__ unsigned s_off;
    const int t = threadIdx.x;
    unsigned c = (t < nb) ? bsum[t] : 0u;
    sh[t] = c;
    __syncthreads();
    unsigned incl = c;
    for (int off = 1; off < 256; off <<= 1) {
        unsigned v = (t >= off) ? sh[t - off] : 0u;
        __syncthreads();
        incl += v;
        sh[t] = incl;
        __syncthreads();
    }
    if (t == 0) {
        s_off = (blockIdx.x > 0) ? sh[blockIdx.x - 1] : 0u;
        if (blockIdx.x == 0) rowptr[NN] = NE;
    }
    __syncthreads();
    int i = blockIdx.x * 256 + t;
    if (i < NN) rowptr[i] += s_off;
}

// scatter + inverse map jof: edge e lands at perm position jof[e]
__global__ __launch_bounds__(256) void scatter_kernel(
    const int* __restrict__ receivers, const unsigned* __restrict__ rowptr,
    unsigned* __restrict__ cnt2, unsigned* __restrict__ jof)
{
    int i = blockIdx.x * 256 + threadIdx.x;
    if (i >= NE) return;
    int r = receivers[i];
    unsigned pos = rowptr[r] + atomicAdd(&cnt2[r], 1u);
    jof[i] = pos;
}

// ---------- both node projections in one kernel ----------
// Sp/Rp layout (bf16, head-interleaved): node row = 64 uints (256 B);
// uint k = l15*4 + h holds cols (32h + l15, 32h + 16 + l15) as 2 bf16.
__global__ __launch_bounds__(256, 4) void proj_both(
    const float* __restrict__ X,
    const bf16x8* __restrict__ Wf0, const bf16x8* __restrict__ Wf1,
    const float* __restrict__ b0, const float* __restrict__ b1,
    int M, uint2* __restrict__ Sp, uint2* __restrict__ Rp)
{
    __shared__ __align__(16) char ldsA[32768];
    const int t = threadIdx.x;
    const int lane = t & 63;
    const int wid = t >> 6;
    const int wr = wid >> 1, wc = wid & 1;
    const int l15 = lane & 15, lgp = lane >> 4;
    const size_t rowbase = (size_t)blockIdx.x * 128;

    #pragma unroll
    for (int i = 0; i < 8; ++i) {
        int c = i * 256 + t;
        int row = c >> 4, cc = c & 15;
        size_t e = rowbase + row;
        uint4 p = make_uint4(0, 0, 0, 0);
        if (e < (size_t)M) {
            const float4* src = (const float4*)(X + e * F + cc * 8);
            float4 f0 = src[0], f1 = src[1];
            p.x = pack2_bf16(f0.x, f0.y);
            p.y = pack2_bf16(f0.z, f0.w);
            p.z = pack2_bf16(f1.x, f1.y);
            p.w = pack2_bf16(f1.z, f1.w);
        }
        unsigned byte = (unsigned)(row * 256 + cc * 16);
        byte ^= (unsigned)((row & 7) << 4);
        *(uint4*)(ldsA + byte) = p;
    }
    __syncthreads();

    #pragma unroll
    for (int pass = 0; pass < 2; ++pass) {
        const bf16x8* Wf = pass ? Wf1 : Wf0;
        const float* bias = pass ? b1 : b0;
        uint2* Y = pass ? Rp : Sp;

        f32x4 acc[4][4];
        #pragma unroll
        for (int n = 0; n < 4; ++n) {
            float bv = bias[wc * 64 + n * 16 + l15];
            #pragma unroll
            for (int m = 0; m < 4; ++m) {
                acc[m][n][0] = bv; acc[m][n][1] = bv;
                acc[m][n][2] = bv; acc[m][n][3] = bv;
            }
        }
        #pragma unroll
        for (int ks = 0; ks < 4; ++ks) {
            const int kb = ks * 64 + lgp * 16;
            bf16x8 af[4], bfr[4];
            #pragma unroll
            for (int m = 0; m < 4; ++m) {
                int row = wr * 64 + m * 16 + l15;
                unsigned byte = ((unsigned)(row * 256 + kb)) ^ ((row & 7) << 4);
                af[m] = *(const bf16x8*)(ldsA + byte);
            }
            #pragma unroll
            for (int n = 0; n < 4; ++n)
                bfr[n] = Wf[((wc * 4 + n) * 4 + ks) * 64 + lane];
            #pragma unroll
            for (int m = 0; m < 4; ++m)
                #pragma unroll
                for (int n = 0; n < 4; ++n)
                    acc[m][n] = __builtin_amdgcn_mfma_f32_16x16x32_bf16(
                        af[m], bfr[n], acc[m][n], 0, 0, 0);
        }
        // store: this thread's cols are heads wc*2 + {0,1}, col-class l15
        #pragma unroll
        for (int m = 0; m < 4; ++m)
            #pragma unroll
            for (int j = 0; j < 4; ++j) {
                int row = wr * 64 + m * 16 + lgp * 4 + j;
                size_t e = rowbase + row;
                if (e >= (size_t)M) continue;
                uint2 pk;
                pk.x = pack2_bf16(acc[m][0][j], acc[m][1][j]);
                pk.y = pack2_bf16(acc[m][2][j], acc[m][3][j]);
                Y[e * 32 + l15 * 2 + wc] = pk;   // uints k = l15*4 + wc*2 + {0,1}
            }
    }
}

// ---------- edge GEMM: BM=64, no LDS/barriers; logits computed here ----------
// 4 waves/block, wave w owns rows w*16..w*16+15 across all 128 cols.
// EA row layout (bf16): uint k = l15*4 + h holds cols (32h+l15, 32h+16+l15).
// Tail also computes the 4 per-head logits (mish + attw dot + DPP reduce
// over the contiguous 16-lane group) and stores float4 logits at jof[e].
__global__ __launch_bounds__(256, 6) void edge_gemm(
    const float* __restrict__ X, const bf16x8* __restrict__ Wf,
    const float* __restrict__ bias,
    const float* __restrict__ attw, const float* __restrict__ attb,
    const int* __restrict__ senders, const int* __restrict__ receivers,
    const unsigned* __restrict__ jof,
    const uint4* __restrict__ Sp4, const uint4* __restrict__ Rp4,
    uint4* __restrict__ EAp, float4* __restrict__ logits4)
{
    const int t = threadIdx.x;
    const int lane = t & 63;
    const int wid = t >> 6;
    const int l15 = lane & 15, lgp = lane >> 4;
    const size_t rowbase = (size_t)blockIdx.x * 64;
    const float* aptr = X + (rowbase + wid * 16 + l15) * F;

    f32x4 acc[8];
    #pragma unroll
    for (int n = 0; n < 8; ++n) {
        float bv = bias[n * 16 + l15];
        acc[n][0] = bv; acc[n][1] = bv; acc[n][2] = bv; acc[n][3] = bv;
    }

    #pragma unroll
    for (int ks = 0; ks < 4; ++ks) {
        const float4* ap = (const float4*)(aptr + ks * 32 + lgp * 8);
        float4 a0 = ap[0], a1 = ap[1];
        uint4 pu;
        pu.x = pack2_bf16(a0.x, a0.y);
        pu.y = pack2_bf16(a0.z, a0.w);
        pu.z = pack2_bf16(a1.x, a1.y);
        pu.w = pack2_bf16(a1.z, a1.w);
        bf16x8 af = __builtin_bit_cast(bf16x8, pu);
        #pragma unroll
        for (int n = 0; n < 8; ++n) {
            bf16x8 bfr = Wf[(n * 4 + ks) * 64 + lane];
            acc[n] = __builtin_amdgcn_mfma_f32_16x16x32_bf16(af, bfr, acc[n], 0, 0, 0);
        }
    }

    // ---- tail: 4 rows per thread (row = wid*16 + lgp*4 + j) ----
    const float aw0 = attw[l15];
    const float aw1 = attw[l15 + 16];
    const float ab0 = attb[0];
    #pragma unroll
    for (int j = 0; j < 4; ++j) {
        int row = wid * 16 + lgp * 4 + j;
        size_t e = rowbase + row;
        int snd = senders[e];          // 16-lane broadcast loads
        int rcv = receivers[e];
        unsigned jj = jof[e];
        uint4 sv = Sp4[(size_t)snd * 16 + l15];
        uint4 rv = Rp4[(size_t)rcv * 16 + l15];
        unsigned uo[4];
        float ph0, ph1, ph2, ph3;
        {
            float elo = acc[0][j] + bf16lo_to_f32(sv.x);
            float ehi = acc[1][j] + bf16hi_to_f32(sv.x);
            uo[0] = pack2_bf16(elo, ehi);
            ph0 = mish_f(elo + bf16lo_to_f32(rv.x)) * aw0
                + mish_f(ehi + bf16hi_to_f32(rv.x)) * aw1;
        }
        {
            float elo = acc[2][j] + bf16lo_to_f32(sv.y);
            float ehi = acc[3][j] + bf16hi_to_f32(sv.y);
            uo[1] = pack2_bf16(elo, ehi);
            ph1 = mish_f(elo + bf16lo_to_f32(rv.y)) * aw0
                + mish_f(ehi + bf16hi_to_f32(rv.y)) * aw1;
        }
        {
            float elo = acc[4][j] + bf16lo_to_f32(sv.z);
            float ehi = acc[5][j] + bf16hi_to_f32(sv.z);
            uo[2] = pack2_bf16(elo, ehi);
            ph2 = mish_f(elo + bf16lo_to_f32(rv.z)) * aw0
                + mish_f(ehi + bf16hi_to_f32(rv.z)) * aw1;
        }
        {
            float elo = acc[6][j] + bf16lo_to_f32(sv.w);
            float ehi = acc[7][j] + bf16hi_to_f32(sv.w);
            uo[3] = pack2_bf16(elo, ehi);
            ph3 = mish_f(elo + bf16lo_to_f32(rv.w)) * aw0
                + mish_f(ehi + bf16hi_to_f32(rv.w)) * aw1;
        }
        EAp[(size_t)jj * 16 + l15] = make_uint4(uo[0], uo[1], uo[2], uo[3]);
        DPP_REDUCE16(ph0);
        DPP_REDUCE16(ph1);
        DPP_REDUCE16(ph2);
        DPP_REDUCE16(ph3);
        if (l15 == 0)
            logits4[jj] = make_float4(ph0 + ab0, ph1 + ab0, ph2 + ab0, ph3 + ab0);
    }
}

// ---------- single-pass softmax + aggregate (logits precomputed) ----------
// One wave per receiver. Per edge: load EA dword + logit, exp, 3 fma.
// 4-deep software pipeline, 4 independent accumulator banks.
__global__ __launch_bounds__(256) void agg_kernel(
    const unsigned* __restrict__ rowptr,
    const float* __restrict__ logits,
    const unsigned* __restrict__ EA, float* __restrict__ out)
{
    const int lane = threadIdx.x & 63;
    const int r = blockIdx.x * 4 + (threadIdx.x >> 6);
    if (r >= NN) return;
    const unsigned start = rowptr[r], end = rowptr[r + 1];

    const int h = lane >> 4;        // head
    const int q = lane & 15;        // col class
    const int k = q * 4 + h;        // dword index within 256B row
    const int c0 = 32 * h + q;

    if (start == end) {
        out[(size_t)r * HD + c0]      = 0.f;
        out[(size_t)r * HD + c0 + 16] = 0.f;
        return;
    }

    const unsigned* ea = EA + k;
    const float* lg = logits + h;

#define PROC(P, L, AX, AY, DN) do {                                          \
        float w_ = __expf(L);                                                \
        float el_ = bf16lo_to_f32(P), eh_ = bf16hi_to_f32(P);                \
        DN += w_; AX += w_ * el_; AY += w_ * eh_; } while (0)

    float ax0 = 0.f, ay0 = 0.f, dn0 = 0.f;
    float ax1 = 0.f, ay1 = 0.f, dn1 = 0.f;
    float ax2 = 0.f, ay2 = 0.f, dn2 = 0.f;
    float ax3 = 0.f, ay3 = 0.f, dn3 = 0.f;

    unsigned cnt = end - start;
    unsigned nq = cnt >> 2;
    unsigned j = start;
    if (nq) {
        const unsigned* e0 = ea + (size_t)start * 64;
        const float* g0 = lg + (size_t)start * 4;
        unsigned p0 = e0[0], p1 = e0[64], p2 = e0[128], p3 = e0[192];
        float l0 = g0[0], l1 = g0[4], l2 = g0[8], l3 = g0[12];
        for (unsigned qq = 1; qq < nq; ++qq) {
            const unsigned* en = ea + (size_t)(start + qq * 4) * 64;
            const float* gn = lg + (size_t)(start + qq * 4) * 4;
            unsigned n0 = en[0], n1 = en[64], n2 = en[128], n3 = en[192];
            float m0 = gn[0], m1 = gn[4], m2 = gn[8], m3 = gn[12];
            PROC(p0, l0, ax0, ay0, dn0);
            PROC(p1, l1, ax1, ay1, dn1);
            PROC(p2, l2, ax2, ay2, dn2);
            PROC(p3, l3, ax3, ay3, dn3);
            p0 = n0; p1 = n1; p2 = n2; p3 = n3;
            l0 = m0; l1 = m1; l2 = m2; l3 = m3;
        }
        PROC(p0, l0, ax0, ay0, dn0);
        PROC(p1, l1, ax1, ay1, dn1);
        PROC(p2, l2, ax2, ay2, dn2);
        PROC(p3, l3, ax3, ay3, dn3);
        j = start + nq * 4;
    }
    for (; j < end; ++j) {
        unsigned p = ea[(size_t)j * 64];
        float l = lg[(size_t)j * 4];
        PROC(p, l, ax0, ay0, dn0);
    }
#undef PROC

    float rd = 1.f / (dn0 + dn1 + dn2 + dn3);
    out[(size_t)r * HD + c0]      = (ax0 + ax1 + ax2 + ax3) * rd;
    out[(size_t)r * HD + c0 + 16] = (ay0 + ay1 + ay2 + ay3) * rd;
}

// ---------- host ----------
extern "C" void kernel_launch(void* const* d_in, const int* in_sizes, int n_in,
                              void* d_out, int out_size, void* d_ws, size_t ws_size,
                              hipStream_t stream) {
    const float* nodes = (const float*)d_in[0];
    const float* edges = (const float*)d_in[1];
    const float* Ws_k  = (const float*)d_in[2];
    const float* Ws_b  = (const float*)d_in[3];
    const float* Wr_k  = (const float*)d_in[4];
    const float* Wr_b  = (const float*)d_in[5];
    const float* We_k  = (const float*)d_in[6];
    const float* We_b  = (const float*)d_in[7];
    const float* attw  = (const float*)d_in[8];
    const float* attb  = (const float*)d_in[9];
    const int* senders   = (const int*)d_in[10];
    const int* receivers = (const int*)d_in[11];
    float* out = (float*)d_out;

    char* ws = (char*)d_ws;
    const size_t CNT_OFF  = 0;            // 200,000
    const size_t CNT2_OFF = 200000;       // 200,000
    const size_t RP_OFF   = 400000;       // 200,004
    const size_t BS_OFF   = 600004;       // 1,024 (bsum)
    const size_t JOF_OFF  = 700000;       // 3,200,000 -> ends 3,900,000
    const size_t WF_OFF   = 3900000;      // 98,304    -> ends 3,998,304
    const size_t SP_OFF   = 4000000;      // 12,800,000 (bf16) -> 16.8e6
    const size_t RPP_OFF  = 16800000;     // 12,800,000 -> 29.6e6
    const size_t LG_OFF   = 29600000;     // 12,800,000 -> 42.4e6
    const size_t EA_OFF   = 42400000;     // 204,800,000 -> 247.2e6

    unsigned* cnt    = (unsigned*)(ws + CNT_OFF);
    unsigned* cnt2   = (unsigned*)(ws + CNT2_OFF);
    unsigned* rowptr = (unsigned*)(ws + RP_OFF);
    unsigned* bsum   = (unsigned*)(ws + BS_OFF);
    unsigned* jof    = (unsigned*)(ws + JOF_OFF);
    uint4*    Wf     = (uint4*)(ws + WF_OFF);
    uint2*    Sp     = (uint2*)(ws + SP_OFF);
    uint2*    Rp     = (uint2*)(ws + RPP_OFF);
    float*    logits = (float*)(ws + LG_OFF);
    unsigned* EA     = (unsigned*)(ws + EA_OFF);
    (void)ws_size;

    const int NB = (NN + 255) / 256;   // 196 scan blocks

    // weights -> bf16 fragment order; extra blocks zero cnt/cnt2
    prep_w<<<3 + 98, 256, 0, stream>>>(Ws_k, Wr_k, We_k, Wf, (uint4*)(ws + CNT_OFF));

    // CSR build (rowptr + inverse perm map jof), multi-block scan
    hist_kernel<<<(NE + 255) / 256, 256, 0, stream>>>(receivers, cnt);
    scan1_kernel<<<NB, 256, 0, stream>>>(cnt, rowptr, bsum);
    scan3_kernel<<<NB, 256, 0, stream>>>(rowptr, bsum, NB);
    scatter_kernel<<<(NE + 255) / 256, 256, 0, stream>>>(receivers, rowptr, cnt2, jof);

    // both node projections (bf16 head-interleaved packed output)
    proj_both<<<(NN + 127) / 128, 256, 0, stream>>>(
        nodes, (const bf16x8*)Wf, (const bf16x8*)(Wf + 2048),
        Ws_b, Wr_b, NN, Sp, Rp);

    // edge GEMM: EA + logits written at perm positions
    edge_gemm<<<NE / 64, 256, 0, stream>>>(
        edges, (const bf16x8*)(Wf + 4096), We_b,
        attw, attb, senders, receivers, jof,
        (const uint4*)Sp, (const uint4*)Rp,
        (uint4*)EA, (float4*)logits);

    // single-pass softmax + aggregation (logits precomputed)
    agg_kernel<<<(NN + 3) / 4, 256, 0, stream>>>(
        rowptr, logits, EA, out);
}

// Round 17
// 358.746 us; speedup vs baseline: 1.1029x; 1.1029x over previous
//
#include <hip/hip_runtime.h>
#include <hip/hip_bf16.h>

#define NN 50000
#define NE 800000
#define F 128     // input feature dim (= K)
#define HD 128    // output dim = H*DH (= N)
#define H 4

typedef __attribute__((ext_vector_type(4))) float f32x4;
typedef __attribute__((ext_vector_type(8))) __bf16 bf16x8;
typedef __attribute__((ext_vector_type(2))) __bf16 bf16x2;

// ---------- helpers ----------

// mish(x) = x * tanh(softplus(x)) = x * (u-1)/(u+1), u = (1+e^x)^2
__device__ __forceinline__ float mish_f(float x) {
    if (x > 30.f) return x;
    float t = __expf(x);
    float u = 1.f + t;
    u = u * u;
    return x * (u - 1.f) * __builtin_amdgcn_rcpf(u + 1.f);
}

// packed f32x2 -> bf16x2 (compiler emits v_cvt_pk_bf16_f32, RNE)
__device__ __forceinline__ unsigned pack2_bf16(float a, float b) {
    bf16x2 v;
    v.x = (__bf16)a;
    v.y = (__bf16)b;
    return __builtin_bit_cast(unsigned, v);
}
__device__ __forceinline__ float bf16lo_to_f32(unsigned p) {
    return __uint_as_float((p & 0xFFFFu) << 16);
}
__device__ __forceinline__ float bf16hi_to_f32(unsigned p) {
    return __uint_as_float(p & 0xFFFF0000u);
}

// DPP-based add: v += lane-permuted v within a row of 16 (VALU, no DS)
#define DPP_ADD(v, ctrl)                                                     \
    (v) += __int_as_float(__builtin_amdgcn_update_dpp(                       \
        0, __float_as_int(v), (ctrl), 0xf, 0xf, true))

// ---------- prep: W -> bf16 fragment-ordered; extra blocks zero cnt/cnt2 ----------
__global__ __launch_bounds__(256) void prep_w(
    const float* __restrict__ W0, const float* __restrict__ W1,
    const float* __restrict__ W2, uint4* __restrict__ O,
    uint4* __restrict__ zero_dst)   // 400,000 B = 25,000 uint4
{
    int b = blockIdx.x;
    if (b >= 3) {
        int i = (b - 3) * 256 + threadIdx.x;
        if (i < 25000) zero_dst[i] = make_uint4(0, 0, 0, 0);
        return;
    }
    const float* W = (b == 0) ? W0 : (b == 1) ? W1 : W2;
    uint4* out = O + b * 2048;
    for (int c = threadIdx.x; c < 2048; c += 256) {
        int fn = c >> 8, ks = (c >> 6) & 3, lane = c & 63;
        int lgp = lane >> 4, l15 = lane & 15;
        int col = fn * 16 + l15, k0 = ks * 32 + lgp * 8;
        unsigned u[4];
        #pragma unroll
        for (int i = 0; i < 4; ++i)
            u[i] = pack2_bf16(W[(k0 + 2 * i) * 128 + col],
                              W[(k0 + 2 * i + 1) * 128 + col]);
        out[c] = make_uint4(u[0], u[1], u[2], u[3]);
    }
}

// ---------- CSR build ----------
__global__ __launch_bounds__(256) void hist_kernel(
    const int* __restrict__ receivers, unsigned* __restrict__ cnt)
{
    int i = blockIdx.x * 256 + threadIdx.x;
    if (i < NE) atomicAdd(&cnt[receivers[i]], 1u);
}

// scan phase 1: per-block exclusive scan of 256 counts + block sum
__global__ __launch_bounds__(256) void scan1_kernel(
    const unsigned* __restrict__ cnt, unsigned* __restrict__ rowptr,
    unsigned* __restrict__ bsum)
{
    __shared__ unsigned sh[256];
    const int t = threadIdx.x;
    int i = blockIdx.x * 256 + t;
    unsigned c = (i < NN) ? cnt[i] : 0u;
    sh[t] = c;
    __syncthreads();
    unsigned incl = c;
    for (int off = 1; off < 256; off <<= 1) {
        unsigned v = (t >= off) ? sh[t - off] : 0u;
        __syncthreads();
        incl += v;
        sh[t] = incl;
        __syncthreads();
    }
    if (i < NN) rowptr[i] = incl - c;      // exclusive within block
    if (t == 255) bsum[blockIdx.x] = incl; // block total
}

// scan phase 2+3 fused: each block redundantly scans the block sums,
// picks its own offset, adds it.
__global__ __launch_bounds__(256) void scan3_kernel(
    unsigned* __restrict__ rowptr, const unsigned* __restrict__ bsum, int nb)
{
    __shared__ unsigned sh[256];
    __shared__ unsigned s_off;
    const int t = threadIdx.x;
    unsigned c = (t < nb) ? bsum[t] : 0u;
    sh[t] = c;
    __syncthreads();
    unsigned incl = c;
    for (int off = 1; off < 256; off <<= 1) {
        unsigned v = (t >= off) ? sh[t - off] : 0u;
        __syncthreads();
        incl += v;
        sh[t] = incl;
        __syncthreads();
    }
    if (t == 0) {
        s_off = (blockIdx.x > 0) ? sh[blockIdx.x - 1] : 0u;
        if (blockIdx.x == 0) rowptr[NN] = NE;
    }
    __syncthreads();
    int i = blockIdx.x * 256 + t;
    if (i < NN) rowptr[i] += s_off;
}

// scatter + inverse map jof: edge e lands at perm position jof[e]
__global__ __launch_bounds__(256) void scatter_kernel(
    const int* __restrict__ receivers, const unsigned* __restrict__ rowptr,
    unsigned* __restrict__ cnt2, unsigned* __restrict__ jof)
{
    int i = blockIdx.x * 256 + threadIdx.x;
    if (i >= NE) return;
    int r = receivers[i];
    unsigned pos = rowptr[r] + atomicAdd(&cnt2[r], 1u);
    jof[i] = pos;
}

// ---------- both node projections in one kernel ----------
// Sp/Rp layout (bf16, head-interleaved): node row = 64 uints (256 B);
// uint k = l15*4 + h holds cols (32h + l15, 32h + 16 + l15) as 2 bf16.
__global__ __launch_bounds__(256, 4) void proj_both(
    const float* __restrict__ X,
    const bf16x8* __restrict__ Wf0, const bf16x8* __restrict__ Wf1,
    const float* __restrict__ b0, const float* __restrict__ b1,
    int M, uint2* __restrict__ Sp, uint2* __restrict__ Rp)
{
    __shared__ __align__(16) char ldsA[32768];
    const int t = threadIdx.x;
    const int lane = t & 63;
    const int wid = t >> 6;
    const int wr = wid >> 1, wc = wid & 1;
    const int l15 = lane & 15, lgp = lane >> 4;
    const size_t rowbase = (size_t)blockIdx.x * 128;

    #pragma unroll
    for (int i = 0; i < 8; ++i) {
        int c = i * 256 + t;
        int row = c >> 4, cc = c & 15;
        size_t e = rowbase + row;
        uint4 p = make_uint4(0, 0, 0, 0);
        if (e < (size_t)M) {
            const float4* src = (const float4*)(X + e * F + cc * 8);
            float4 f0 = src[0], f1 = src[1];
            p.x = pack2_bf16(f0.x, f0.y);
            p.y = pack2_bf16(f0.z, f0.w);
            p.z = pack2_bf16(f1.x, f1.y);
            p.w = pack2_bf16(f1.z, f1.w);
        }
        unsigned byte = (unsigned)(row * 256 + cc * 16);
        byte ^= (unsigned)((row & 7) << 4);
        *(uint4*)(ldsA + byte) = p;
    }
    __syncthreads();

    #pragma unroll
    for (int pass = 0; pass < 2; ++pass) {
        const bf16x8* Wf = pass ? Wf1 : Wf0;
        const float* bias = pass ? b1 : b0;
        uint2* Y = pass ? Rp : Sp;

        f32x4 acc[4][4];
        #pragma unroll
        for (int n = 0; n < 4; ++n) {
            float bv = bias[wc * 64 + n * 16 + l15];
            #pragma unroll
            for (int m = 0; m < 4; ++m) {
                acc[m][n][0] = bv; acc[m][n][1] = bv;
                acc[m][n][2] = bv; acc[m][n][3] = bv;
            }
        }
        #pragma unroll
        for (int ks = 0; ks < 4; ++ks) {
            const int kb = ks * 64 + lgp * 16;
            bf16x8 af[4], bfr[4];
            #pragma unroll
            for (int m = 0; m < 4; ++m) {
                int row = wr * 64 + m * 16 + l15;
                unsigned byte = ((unsigned)(row * 256 + kb)) ^ ((row & 7) << 4);
                af[m] = *(const bf16x8*)(ldsA + byte);
            }
            #pragma unroll
            for (int n = 0; n < 4; ++n)
                bfr[n] = Wf[((wc * 4 + n) * 4 + ks) * 64 + lane];
            #pragma unroll
            for (int m = 0; m < 4; ++m)
                #pragma unroll
                for (int n = 0; n < 4; ++n)
                    acc[m][n] = __builtin_amdgcn_mfma_f32_16x16x32_bf16(
                        af[m], bfr[n], acc[m][n], 0, 0, 0);
        }
        // store: this thread's cols are heads wc*2 + {0,1}, col-class l15
        #pragma unroll
        for (int m = 0; m < 4; ++m)
            #pragma unroll
            for (int j = 0; j < 4; ++j) {
                int row = wr * 64 + m * 16 + lgp * 4 + j;
                size_t e = rowbase + row;
                if (e >= (size_t)M) continue;
                uint2 pk;
                pk.x = pack2_bf16(acc[m][0][j], acc[m][1][j]);
                pk.y = pack2_bf16(acc[m][2][j], acc[m][3][j]);
                Y[e * 32 + l15 * 2 + wc] = pk;   // uints k = l15*4 + wc*2 + {0,1}
            }
    }
}

// ---------- edge GEMM: BM=64, NO LDS, NO barriers ----------
__global__ __launch_bounds__(256, 8) void edge_gemm(
    const float* __restrict__ X, const bf16x8* __restrict__ Wf,
    const float* __restrict__ bias,
    const int* __restrict__ senders, const unsigned* __restrict__ jof,
    const uint4* __restrict__ Sp4, uint4* __restrict__ EAp)
{
    const int t = threadIdx.x;
    const int lane = t & 63;
    const int wid = t >> 6;
    const int l15 = lane & 15, lgp = lane >> 4;
    const size_t rowbase = (size_t)blockIdx.x * 64;
    const float* aptr = X + (rowbase + wid * 16 + l15) * F;

    f32x4 acc[8];
    #pragma unroll
    for (int n = 0; n < 8; ++n) {
        float bv = bias[n * 16 + l15];
        acc[n][0] = bv; acc[n][1] = bv; acc[n][2] = bv; acc[n][3] = bv;
    }

    #pragma unroll
    for (int ks = 0; ks < 4; ++ks) {
        const float4* ap = (const float4*)(aptr + ks * 32 + lgp * 8);
        float4 a0 = ap[0], a1 = ap[1];
        uint4 pu;
        pu.x = pack2_bf16(a0.x, a0.y);
        pu.y = pack2_bf16(a0.z, a0.w);
        pu.z = pack2_bf16(a1.x, a1.y);
        pu.w = pack2_bf16(a1.z, a1.w);
        bf16x8 af = __builtin_bit_cast(bf16x8, pu);
        #pragma unroll
        for (int n = 0; n < 8; ++n) {
            bf16x8 bfr = Wf[(n * 4 + ks) * 64 + lane];
            acc[n] = __builtin_amdgcn_mfma_f32_16x16x32_bf16(af, bfr, acc[n], 0, 0, 0);
        }
    }

    // ---- tail: 4 rows per thread (row = wid*16 + lgp*4 + j) ----
    #pragma unroll
    for (int j = 0; j < 4; ++j) {
        int row = wid * 16 + lgp * 4 + j;
        size_t e = rowbase + row;
        int snd = senders[e];          // 16-lane broadcast loads
        unsigned jj = jof[e];
        uint4 sv = Sp4[(size_t)snd * 16 + l15];
        unsigned uo[4];
        #pragma unroll
        for (int h = 0; h < 4; ++h) {
            unsigned sp = (h == 0) ? sv.x : (h == 1) ? sv.y : (h == 2) ? sv.z : sv.w;
            float elo = acc[2 * h][j]     + bf16lo_to_f32(sp);
            float ehi = acc[2 * h + 1][j] + bf16hi_to_f32(sp);
            uo[h] = pack2_bf16(elo, ehi);
        }
        EAp[(size_t)jj * 16 + l15] = make_uint4(uo[0], uo[1], uo[2], uo[3]);
    }
}

// ---------- fused logit + single-pass softmax + aggregate ----------
// One wave per receiver; DPP 16-lane reduce; 8-deep software pipeline
// (TWO quads of loads in flight ahead of compute), 4 accumulator banks.
__global__ __launch_bounds__(256) void agg_kernel(
    const unsigned* __restrict__ rowptr,
    const unsigned* __restrict__ Rp32,
    const float* __restrict__ attw, const float* __restrict__ attb,
    const unsigned* __restrict__ EA, float* __restrict__ out)
{
    const int lane = threadIdx.x & 63;
    const int r = blockIdx.x * 4 + (threadIdx.x >> 6);
    if (r >= NN) return;
    const unsigned start = rowptr[r], end = rowptr[r + 1];

    const int h = lane >> 4;        // head
    const int q = lane & 15;        // col class
    const int k = q * 4 + h;        // dword index within 256B row
    const int c0 = 32 * h + q;

    if (start == end) {
        out[(size_t)r * HD + c0]      = 0.f;
        out[(size_t)r * HD + c0 + 16] = 0.f;
        return;
    }

    unsigned rp = Rp32[(size_t)r * 64 + k];
    const float rlo = bf16lo_to_f32(rp), rhi = bf16hi_to_f32(rp);
    const float aw0 = attw[q];
    const float aw1 = attw[q + 16];
    const float ab0 = attb[0];
    const unsigned* ea = EA + k;

#define PROC(P, AX, AY, DN) do {                                             \
        float el_ = bf16lo_to_f32(P), eh_ = bf16hi_to_f32(P);                \
        float tt_ = mish_f(el_ + rlo) * aw0 + mish_f(eh_ + rhi) * aw1;       \
        DPP_ADD(tt_, 0xB1);  DPP_ADD(tt_, 0x4E);                             \
        DPP_ADD(tt_, 0x141); DPP_ADD(tt_, 0x140);                            \
        float w_ = __expf(tt_ + ab0);                                        \
        DN += w_; AX += w_ * el_; AY += w_ * eh_; } while (0)

    float ax0 = 0.f, ay0 = 0.f, dn0 = 0.f;
    float ax1 = 0.f, ay1 = 0.f, dn1 = 0.f;
    float ax2 = 0.f, ay2 = 0.f, dn2 = 0.f;
    float ax3 = 0.f, ay3 = 0.f, dn3 = 0.f;

    unsigned cnt = end - start;
    unsigned nq = cnt >> 2;
    unsigned j = start;
    if (nq >= 2) {
        const unsigned* e0 = ea + (size_t)start * 64;
        const unsigned* e1 = ea + (size_t)(start + 4) * 64;
        unsigned p0 = e0[0], p1 = e0[64], p2 = e0[128], p3 = e0[192];
        unsigned q0 = e1[0], q1 = e1[64], q2 = e1[128], q3 = e1[192];
        for (unsigned qq = 2; qq < nq; ++qq) {
            const unsigned* en = ea + (size_t)(start + qq * 4) * 64;
            unsigned f0 = en[0], f1 = en[64], f2 = en[128], f3 = en[192];
            PROC(p0, ax0, ay0, dn0);
            PROC(p1, ax1, ay1, dn1);
            PROC(p2, ax2, ay2, dn2);
            PROC(p3, ax3, ay3, dn3);
            p0 = q0; p1 = q1; p2 = q2; p3 = q3;
            q0 = f0; q1 = f1; q2 = f2; q3 = f3;
        }
        PROC(p0, ax0, ay0, dn0);
        PROC(p1, ax1, ay1, dn1);
        PROC(p2, ax2, ay2, dn2);
        PROC(p3, ax3, ay3, dn3);
        PROC(q0, ax0, ay0, dn0);
        PROC(q1, ax1, ay1, dn1);
        PROC(q2, ax2, ay2, dn2);
        PROC(q3, ax3, ay3, dn3);
        j = start + nq * 4;
    } else if (nq == 1) {
        const unsigned* e0 = ea + (size_t)start * 64;
        unsigned p0 = e0[0], p1 = e0[64], p2 = e0[128], p3 = e0[192];
        PROC(p0, ax0, ay0, dn0);
        PROC(p1, ax1, ay1, dn1);
        PROC(p2, ax2, ay2, dn2);
        PROC(p3, ax3, ay3, dn3);
        j = start + 4;
    }
    for (; j < end; ++j) {
        unsigned p = ea[(size_t)j * 64];
        PROC(p, ax0, ay0, dn0);
    }
#undef PROC

    float rd = 1.f / (dn0 + dn1 + dn2 + dn3);
    out[(size_t)r * HD + c0]      = (ax0 + ax1 + ax2 + ax3) * rd;
    out[(size_t)r * HD + c0 + 16] = (ay0 + ay1 + ay2 + ay3) * rd;
}

// ---------- host ----------
extern "C" void kernel_launch(void* const* d_in, const int* in_sizes, int n_in,
                              void* d_out, int out_size, void* d_ws, size_t ws_size,
                              hipStream_t stream) {
    const float* nodes = (const float*)d_in[0];
    const float* edges = (const float*)d_in[1];
    const float* Ws_k  = (const float*)d_in[2];
    const float* Ws_b  = (const float*)d_in[3];
    const float* Wr_k  = (const float*)d_in[4];
    const float* Wr_b  = (const float*)d_in[5];
    const float* We_k  = (const float*)d_in[6];
    const float* We_b  = (const float*)d_in[7];
    const float* attw  = (const float*)d_in[8];
    const float* attb  = (const float*)d_in[9];
    const int* senders   = (const int*)d_in[10];
    const int* receivers = (const int*)d_in[11];
    float* out = (float*)d_out;

    char* ws = (char*)d_ws;
    const size_t CNT_OFF  = 0;            // 200,000
    const size_t CNT2_OFF = 200000;       // 200,000
    const size_t RP_OFF   = 400000;       // 200,004
    const size_t BS_OFF   = 600004;       // 1,024 (bsum)
    const size_t JOF_OFF  = 700000;       // 3,200,000 -> ends 3,900,000
    const size_t WF_OFF   = 3900000;      // 98,304    -> ends 3,998,304
    const size_t SP_OFF   = 4000000;      // 12,800,000 (bf16) -> 16.8e6
    const size_t RPP_OFF  = 16800000;     // 12,800,000 -> 29.6e6
    const size_t EA_OFF   = 29600000;     // 204,800,000 -> 234.4e6

    unsigned* cnt    = (unsigned*)(ws + CNT_OFF);
    unsigned* cnt2   = (unsigned*)(ws + CNT2_OFF);
    unsigned* rowptr = (unsigned*)(ws + RP_OFF);
    unsigned* bsum   = (unsigned*)(ws + BS_OFF);
    unsigned* jof    = (unsigned*)(ws + JOF_OFF);
    uint4*    Wf     = (uint4*)(ws + WF_OFF);
    uint2*    Sp     = (uint2*)(ws + SP_OFF);
    uint2*    Rp     = (uint2*)(ws + RPP_OFF);
    unsigned* EA     = (unsigned*)(ws + EA_OFF);
    (void)ws_size;

    const int NB = (NN + 255) / 256;   // 196 scan blocks

    // weights -> bf16 fragment order; extra blocks zero cnt/cnt2
    prep_w<<<3 + 98, 256, 0, stream>>>(Ws_k, Wr_k, We_k, Wf, (uint4*)(ws + CNT_OFF));

    // CSR build (rowptr + inverse perm map jof), multi-block scan
    hist_kernel<<<(NE + 255) / 256, 256, 0, stream>>>(receivers, cnt);
    scan1_kernel<<<NB, 256, 0, stream>>>(cnt, rowptr, bsum);
    scan3_kernel<<<NB, 256, 0, stream>>>(rowptr, bsum, NB);
    scatter_kernel<<<(NE + 255) / 256, 256, 0, stream>>>(receivers, rowptr, cnt2, jof);

    // both node projections (bf16 head-interleaved packed output)
    proj_both<<<(NN + 127) / 128, 256, 0, stream>>>(
        nodes, (const bf16x8*)Wf, (const bf16x8*)(Wf + 2048),
        Ws_b, Wr_b, NN, Sp, Rp);

    // edge GEMM: EA written at perm positions (no LDS, no barriers)
    edge_gemm<<<NE / 64, 256, 0, stream>>>(
        edges, (const bf16x8*)(Wf + 4096), We_b,
        senders, jof, (const uint4*)Sp, (uint4*)EA);

    // fused logit + single-pass softmax + aggregation (8-deep pipeline)
    agg_kernel<<<(NN + 3) / 4, 256, 0, stream>>>(
        rowptr, (const unsigned*)Rp, attw, attb, EA, out);
}